// Round 3
// baseline (573.404 us; speedup 1.0000x reference)
//
#include <hip/hip_runtime.h>
#include <hip/hip_cooperative_groups.h>
#include <math.h>

namespace cg = cooperative_groups;

constexpr int N_NODES = 2000;
constexpr int F_IN    = 512;
constexpr int H       = 64;
constexpr int SLOT_SH = 8;      // 256 slots/node in slot-CSR (max deg ~105)
constexpr int NBLK    = 256;    // one block per CU, co-resident
constexpr int NTHR    = 512;

struct FusedParams {
  const float* real; const float* imag;
  const int*   ei;   const float* ew;
  const float* W1;   const float* W2;
  const float* lw;   const float* lb;
  float* deg; int* cnt;
  int*   nbr; float* cra; float* cia;
  float* P0r; float* P0i; float* P1r; float* P1i;   // contiguous block!
  float* xr1; float* xi1;
  float4* nuw;
  int E;
};

// --------------------------------------------------------------- GEMM tile
// C[64 x 64] tile of A[M x K] @ W[K x 64]; 512 threads: 16 cols x 32 row-pairs
__device__ __forceinline__ void gemm_tile(
    const float* __restrict__ A, const float* __restrict__ W,
    float (*As)[65], float (*Ws)[64],
    int r0, int kbeg, int kend, int K,
    float* __restrict__ C, bool atomic)
{
  int t  = threadIdx.x;
  int tx = t & 15, ty = t >> 4;          // tx: col group, ty: 0..31 row pair
  float acc[2][4] = {};
  for (int k0 = kbeg; k0 < kend; k0 += 64) {
    #pragma unroll
    for (int i = 0; i < 8; i++) {
      int idx = t + i * NTHR;
      int row = idx >> 6, kk = idx & 63;
      int gr = r0 + row;
      As[row][kk] = (gr < N_NODES) ? A[(size_t)gr * K + k0 + kk] : 0.f;
    }
    #pragma unroll
    for (int i = 0; i < 8; i++) {
      int idx = t + i * NTHR;
      int kk = idx >> 6, col = idx & 63;
      Ws[kk][col] = W[(size_t)(k0 + kk) * H + col];
    }
    __syncthreads();
    #pragma unroll
    for (int kk = 0; kk < 64; kk++) {
      float4 wv = *reinterpret_cast<const float4*>(&Ws[kk][tx * 4]);
      float a0 = As[ty * 2 + 0][kk];
      float a1 = As[ty * 2 + 1][kk];
      acc[0][0] = fmaf(a0, wv.x, acc[0][0]);
      acc[0][1] = fmaf(a0, wv.y, acc[0][1]);
      acc[0][2] = fmaf(a0, wv.z, acc[0][2]);
      acc[0][3] = fmaf(a0, wv.w, acc[0][3]);
      acc[1][0] = fmaf(a1, wv.x, acc[1][0]);
      acc[1][1] = fmaf(a1, wv.y, acc[1][1]);
      acc[1][2] = fmaf(a1, wv.z, acc[1][2]);
      acc[1][3] = fmaf(a1, wv.w, acc[1][3]);
    }
    __syncthreads();
  }
  #pragma unroll
  for (int r = 0; r < 2; r++) {
    int gr = r0 + ty * 2 + r;
    if (gr < N_NODES) {
      size_t o = (size_t)gr * H + tx * 4;
      if (atomic) {
        atomicAdd(&C[o + 0], acc[r][0]);
        atomicAdd(&C[o + 1], acc[r][1]);
        atomicAdd(&C[o + 2], acc[r][2]);
        atomicAdd(&C[o + 3], acc[r][3]);
      } else {
        *reinterpret_cast<float4*>(&C[o]) =
            make_float4(acc[r][0], acc[r][1], acc[r][2], acc[r][3]);
      }
    }
  }
}

// --------------------------------------- neighbor aggregation + add + ReLU
__device__ __forceinline__ void aggregate(
    const FusedParams& p, int v, int h, float& aro, float& aio)
{
  int cv = p.cnt[v];
  float ar = 0.f, ai = 0.f;
  for (int j = 0; j < cv; j++) {
    int idx = (v << SLOT_SH) + j;
    int u = p.nbr[idx];
    float cr = p.cra[idx], ci = p.cia[idx];
    float pr = p.P1r[u * H + h];
    float pi = p.P1i[u * H + h];
    ar = fmaf(cr, pr, ar); ar = fmaf(-ci, pi, ar);
    ai = fmaf(cr, pi, ai); ai = fmaf( ci, pr, ai);
  }
  ar += p.P0r[v * H + h];
  ai += p.P0i[v * H + h];
  if (ar < 0.f) { ar = 0.f; ai = 0.f; }
  aro = ar; aio = ai;
}

// ------------------------------------------------------- fused GNN kernel
__global__ __launch_bounds__(NTHR) void fused_kernel(FusedParams p)
{
  cg::grid_group grid = cg::this_grid();
  __shared__ float As[64][65];
  __shared__ float Ws[64][64];
  int t    = threadIdx.x;
  int gtid = blockIdx.x * NTHR + t;   // 0 .. 131071

  // ---- P0: zero deg/cnt and the 4 contiguous P arrays (128000 float4)
  if (gtid < 2048) { p.deg[gtid] = 0.f; p.cnt[gtid] = 0; }
  {
    float4* p4 = reinterpret_cast<float4*>(p.P0r);
    for (int i = gtid; i < N_NODES * H; i += NBLK * NTHR)
      p4[i] = make_float4(0.f, 0.f, 0.f, 0.f);
  }
  __threadfence();
  grid.sync();

  // ---- P1: absolute symmetrized degrees
  for (int e = gtid; e < p.E; e += NBLK * NTHR) {
    int s = p.ei[e], d = p.ei[p.E + e];
    float aw = fabsf(0.5f * p.ew[e]);
    atomicAdd(&p.deg[d], aw);
    atomicAdd(&p.deg[s], aw);
  }
  __threadfence();
  grid.sync();

  // ---- P2: slot-CSR build with fused dinv
  for (int e = gtid; e < p.E; e += NBLK * NTHR) {
    int s = p.ei[e], d = p.ei[p.E + e];
    float ww = p.ew[e];
    float degs = p.deg[s], degd = p.deg[d];
    float dvs = (degs > 0.f) ? rsqrtf(degs) : 0.f;
    float dvd = (degd > 0.f) ? rsqrtf(degd) : 0.f;
    float norm = 0.5f * ww * dvs * dvd;
    float sn, cs;
    sincosf(1.5707963267948966f * ww, &sn, &cs);
    float cr = -norm * cs;
    float ci = -norm * sn;
    int p1 = atomicAdd(&p.cnt[d], 1);
    int i1 = (d << SLOT_SH) + p1;
    p.nbr[i1] = s; p.cra[i1] = cr; p.cia[i1] = ci;
    int p2 = atomicAdd(&p.cnt[s], 1);
    int i2 = (s << SLOT_SH) + p2;
    p.nbr[i2] = d; p.cra[i2] = cr; p.cia[i2] = -ci;
  }
  __threadfence();
  grid.sync();

  // ---- P3: layer-1 GEMMs (K=512, K-split 2, atomic epilogue)
  {
    int bi    = blockIdx.x;          // 256 = 4 matrices x 32 tiles x 2 ksplit
    int which = bi & 3;
    int tile  = (bi >> 2) & 31;
    int kz    = bi >> 7;
    const float* A = (which & 1) ? p.imag : p.real;
    const float* W = p.W1 + (size_t)(which >> 1) * F_IN * H;
    float* C = (which == 0) ? p.P0r : (which == 1) ? p.P0i
             : (which == 2) ? p.P1r : p.P1i;
    gemm_tile(A, W, As, Ws, tile * 64, kz * 256, kz * 256 + 256, F_IN, C, true);
  }
  __threadfence();
  grid.sync();

  // ---- P4: layer-1 aggregation (wave per node)
  {
    int wid = gtid >> 6, h = t & 63;
    if (wid < N_NODES) {
      float ar, ai;
      aggregate(p, wid, h, ar, ai);
      p.xr1[wid * H + h] = ar;
      p.xi1[wid * H + h] = ai;
    }
  }
  __threadfence();
  grid.sync();

  // ---- P5: layer-2 GEMMs (K=64, 128 active blocks, plain store)
  if (blockIdx.x < 128) {
    int bi    = blockIdx.x;
    int which = bi & 3;
    int tile  = bi >> 2;
    const float* A = (which & 1) ? p.xi1 : p.xr1;
    const float* W = p.W2 + (size_t)(which >> 1) * H * H;
    float* C = (which == 0) ? p.P0r : (which == 1) ? p.P0i
             : (which == 2) ? p.P1r : p.P1i;
    gemm_tile(A, W, As, Ws, tile * 64, 0, H, H, C, false);
  }
  __threadfence();
  grid.sync();

  // ---- P6: layer-2 aggregation + per-node partial logits (u, w)
  {
    int wid = gtid >> 6, h = t & 63;
    if (wid < N_NODES) {
      float ar, ai;
      aggregate(p, wid, h, ar, ai);
      const float2* lw2 = reinterpret_cast<const float2*>(p.lw);
      float2 l0 = lw2[h], l1 = lw2[64 + h], l2 = lw2[128 + h], l3 = lw2[192 + h];
      float u0 = ar * l0.x + ai * l2.x;
      float u1 = ar * l0.y + ai * l2.y;
      float w0 = ar * l1.x + ai * l3.x;
      float w1 = ar * l1.y + ai * l3.y;
      #pragma unroll
      for (int off = 1; off < 64; off <<= 1) {
        u0 += __shfl_xor(u0, off, 64);
        u1 += __shfl_xor(u1, off, 64);
        w0 += __shfl_xor(w0, off, 64);
        w1 += __shfl_xor(w1, off, 64);
      }
      if (h == 0)
        p.nuw[wid] = make_float4(u0 + p.lb[0], u1 + p.lb[1], w0, w1);
    }
  }
}

// -------------------------------------------------------------- query head
// 16 lanes per query (float4/lane of the 256B sim row); grid-stride.
__global__ __launch_bounds__(256) void query_kernel(
    const int* __restrict__ qe, const float* __restrict__ emb,
    const float* __restrict__ lw, const float4* __restrict__ nuw,
    float2* __restrict__ out, int Qn, int n)
{
  const float2* lw2 = reinterpret_cast<const float2*>(lw);
  int l = threadIdx.x & 15;
  float2 wa = lw2[256 + 4 * l];
  float2 wb = lw2[257 + 4 * l];
  float2 wc = lw2[258 + 4 * l];
  float2 wd = lw2[259 + 4 * l];
  int q0    = (blockIdx.x * 256 + threadIdx.x) >> 4;
  int qstep = (gridDim.x * 256) >> 4;
  const float4* emb4 = reinterpret_cast<const float4*>(emb);
  for (int gq = q0; gq < Qn; gq += qstep) {
    int ni = qe[2 * gq], nj = qe[2 * gq + 1];
    float4 s4 = emb4[((size_t)ni * n + nj) * 16 + l];
    float acc0 = s4.x * wa.x + s4.y * wb.x + s4.z * wc.x + s4.w * wd.x;
    float acc1 = s4.x * wa.y + s4.y * wb.y + s4.z * wc.y + s4.w * wd.y;
    #pragma unroll
    for (int off = 1; off < 16; off <<= 1) {
      acc0 += __shfl_xor(acc0, off, 64);
      acc1 += __shfl_xor(acc1, off, 64);
    }
    if (l == 0) {
      float4 uni = nuw[ni];
      float4 unj = nuw[nj];
      float lg0 = acc0 + uni.x + unj.z;
      float lg1 = acc1 + uni.y + unj.w;
      float m = fmaxf(lg0, lg1);
      float lse = m + logf(expf(lg0 - m) + expf(lg1 - m));
      out[gq] = make_float2(lg0 - lse, lg1 - lse);
    }
  }
}

// ------------------------------------------------------------------- launcher
extern "C" void kernel_launch(void* const* d_in, const int* in_sizes, int n_in,
                              void* d_out, int out_size, void* d_ws, size_t ws_size,
                              hipStream_t stream)
{
  FusedParams fp;
  fp.real = (const float*)d_in[0];
  fp.imag = (const float*)d_in[1];
  fp.ei   = (const int*)d_in[2];
  const int* qe = (const int*)d_in[3];
  const float* emb = (const float*)d_in[4];
  fp.ew   = (const float*)d_in[5];
  fp.W1   = (const float*)d_in[6];
  fp.W2   = (const float*)d_in[7];
  fp.lw   = (const float*)d_in[8];
  fp.lb   = (const float*)d_in[9];
  float2* out = (float2*)d_out;

  fp.E  = in_sizes[2] / 2;
  int Q = in_sizes[3] / 2;
  int n = N_NODES;
  int nslots = N_NODES << SLOT_SH;   // 512000

  char* ws = (char*)d_ws;
  size_t off = 0;
  auto alloc = [&](size_t bytes) -> char* {
    char* p = ws + off;
    off = (off + bytes + 255) & ~(size_t)255;
    return p;
  };
  fp.deg = (float*)alloc(2048 * 4);
  fp.cnt = (int*)  alloc(2048 * 4);
  // P0r..P1i MUST be contiguous (fused zero phase relies on it);
  // each is 512000 B (multiple of 256) so alloc() keeps them adjacent.
  fp.P0r = (float*)alloc((size_t)N_NODES * H * 4);
  fp.P0i = (float*)alloc((size_t)N_NODES * H * 4);
  fp.P1r = (float*)alloc((size_t)N_NODES * H * 4);
  fp.P1i = (float*)alloc((size_t)N_NODES * H * 4);
  fp.nbr = (int*)  alloc((size_t)nslots * 4);
  fp.cra = (float*)alloc((size_t)nslots * 4);
  fp.cia = (float*)alloc((size_t)nslots * 4);
  fp.xr1 = (float*)alloc((size_t)N_NODES * H * 4);
  fp.xi1 = (float*)alloc((size_t)N_NODES * H * 4);
  fp.nuw = (float4*)alloc((size_t)N_NODES * 16);

  void* kargs[] = { &fp };
  hipLaunchCooperativeKernel((const void*)fused_kernel,
                             dim3(NBLK), dim3(NTHR), kargs, 0, stream);

  query_kernel<<<2048, 256, 0, stream>>>(qe, emb, fp.lw, fp.nuw, out, Q, n);
}

// Round 4
// 144.425 us; speedup vs baseline: 3.9703x; 3.9703x over previous
//
#include <hip/hip_runtime.h>
#include <math.h>

constexpr int N_NODES = 2000;
constexpr int F_IN    = 512;
constexpr int H       = 64;
constexpr int SLOT_SH = 8;     // 256 slots/node (max degree ~105 << 256)

// --------------------------------------------------------------- GEMM tile
// C[64x64] tile of A[M x K] @ W[K x 64], 256 threads, 4x4 micro-tile,
// full-K loop, plain float4 store (no zero-init needed).
__device__ __forceinline__ void gemm_tile256(
    const float* __restrict__ A, const float* __restrict__ W,
    float (*As)[65], float (*Ws)[64],
    int r0, int K, float* __restrict__ C)
{
  int t  = threadIdx.x;
  int tx = t & 15, ty = t >> 4;
  float acc[4][4] = {};
  for (int k0 = 0; k0 < K; k0 += 64) {
    #pragma unroll
    for (int i = 0; i < 16; i++) {
      int idx = t + i * 256;
      int row = idx >> 6, kk = idx & 63;
      int gr = r0 + row;
      As[row][kk] = (gr < N_NODES) ? A[(size_t)gr * K + k0 + kk] : 0.f;
    }
    #pragma unroll
    for (int i = 0; i < 16; i++) {
      int idx = t + i * 256;
      int kk = idx >> 6, col = idx & 63;
      Ws[kk][col] = W[(size_t)(k0 + kk) * H + col];
    }
    __syncthreads();
    #pragma unroll
    for (int kk = 0; kk < 64; kk++) {
      float4 wv = *reinterpret_cast<const float4*>(&Ws[kk][tx * 4]);
      float av[4];
      #pragma unroll
      for (int r = 0; r < 4; r++) av[r] = As[ty * 4 + r][kk];
      #pragma unroll
      for (int r = 0; r < 4; r++) {
        acc[r][0] = fmaf(av[r], wv.x, acc[r][0]);
        acc[r][1] = fmaf(av[r], wv.y, acc[r][1]);
        acc[r][2] = fmaf(av[r], wv.z, acc[r][2]);
        acc[r][3] = fmaf(av[r], wv.w, acc[r][3]);
      }
    }
    __syncthreads();
  }
  #pragma unroll
  for (int r = 0; r < 4; r++) {
    int gr = r0 + ty * 4 + r;
    if (gr < N_NODES) {
      *reinterpret_cast<float4*>(&C[(size_t)gr * H + tx * 4]) =
          make_float4(acc[r][0], acc[r][1], acc[r][2], acc[r][3]);
    }
  }
}

// ------------------------------------------------- fused GEMM1 + deg/CSR build
// Blocks [0,128): the 4 layer-1 GEMMs (real/imag x W1-half), 32 tiles each.
// Blocks [128, 128+ceil(E/256)): edge pass — degree atomics + slot-CSR with
// UNSCALED coeffs cr' = -0.5w cos(pi w/2), ci' = -0.5w sin(pi w/2)
// (dinv applied later at aggregation; removes the deg->build dependency).
__global__ __launch_bounds__(256) void fused1_kernel(
    const float* __restrict__ real, const float* __restrict__ imag,
    const float* __restrict__ W1,
    const int* __restrict__ ei, const float* __restrict__ ew,
    float* __restrict__ deg, int* __restrict__ cnt,
    int* __restrict__ nbr, float* __restrict__ cra, float* __restrict__ cia,
    float* __restrict__ P0r, float* __restrict__ P0i,
    float* __restrict__ P1r, float* __restrict__ P1i, int E)
{
  __shared__ float As[64][65];
  __shared__ float Ws[64][64];
  if (blockIdx.x < 128) {
    int bi = blockIdx.x;
    int which = bi & 3, tile = bi >> 2;
    const float* A = (which & 1) ? imag : real;
    const float* W = W1 + (size_t)(which >> 1) * F_IN * H;
    float* C = (which == 0) ? P0r : (which == 1) ? P0i
             : (which == 2) ? P1r : P1i;
    gemm_tile256(A, W, As, Ws, tile * 64, F_IN, C);
  } else {
    int e = (blockIdx.x - 128) * 256 + threadIdx.x;
    if (e < E) {
      int s = ei[e], d = ei[E + e];
      float ww = ew[e];
      float aw = fabsf(0.5f * ww);
      atomicAdd(&deg[d], aw);
      atomicAdd(&deg[s], aw);
      float sn, cs;
      sincosf(1.5707963267948966f * ww, &sn, &cs);
      float cr = -0.5f * ww * cs;
      float ci = -0.5f * ww * sn;
      int p1 = atomicAdd(&cnt[d], 1);
      int i1 = (d << SLOT_SH) + p1;
      nbr[i1] = s; cra[i1] = cr; cia[i1] = ci;
      int p2 = atomicAdd(&cnt[s], 1);
      int i2 = (s << SLOT_SH) + p2;
      nbr[i2] = d; cra[i2] = cr; cia[i2] = -ci;
    }
  }
}

// ------------------------------- aggregation core (block/node, 4-wave split)
// partial = sum_j dinv[u_j] * (cr' x_r[u] - ci' x_i[u], ...); final wave
// multiplies by dinv[v], adds P0 and applies the complex ReLU.
__device__ __forceinline__ void agg_partial(
    const int* __restrict__ cnt, const int* __restrict__ nbr,
    const float* __restrict__ cra, const float* __restrict__ cia,
    const float* __restrict__ deg,
    const float* __restrict__ Pr, const float* __restrict__ Pi,
    int v, int h, int wv, float& aro, float& aio)
{
  int cv = cnt[v];
  float ar = 0.f, ai = 0.f;
  for (int j = wv; j < cv; j += 4) {
    int idx = (v << SLOT_SH) + j;
    int u = nbr[idx];
    float dg = deg[u];
    float du = (dg > 0.f) ? rsqrtf(dg) : 0.f;
    float cr = cra[idx] * du, ci = cia[idx] * du;
    float pr = Pr[u * H + h];
    float pi = Pi[u * H + h];
    ar = fmaf(cr, pr, ar); ar = fmaf(-ci, pi, ar);
    ai = fmaf(cr, pi, ai); ai = fmaf( ci, pr, ai);
  }
  aro = ar; aio = ai;
}

__global__ __launch_bounds__(256) void aggregate1_kernel(
    const int* __restrict__ cnt, const int* __restrict__ nbr,
    const float* __restrict__ cra, const float* __restrict__ cia,
    const float* __restrict__ deg,
    const float* __restrict__ P0r, const float* __restrict__ P0i,
    const float* __restrict__ P1r, const float* __restrict__ P1i,
    float* __restrict__ xr, float* __restrict__ xi)
{
  __shared__ float sr[4][64], si[4][64];
  int v = blockIdx.x;
  int h = threadIdx.x & 63;
  int wv = threadIdx.x >> 6;
  float ar, ai;
  agg_partial(cnt, nbr, cra, cia, deg, P1r, P1i, v, h, wv, ar, ai);
  sr[wv][h] = ar; si[wv][h] = ai;
  __syncthreads();
  if (wv == 0) {
    float dgv = deg[v];
    float dv = (dgv > 0.f) ? rsqrtf(dgv) : 0.f;
    ar = (sr[0][h] + sr[1][h] + sr[2][h] + sr[3][h]) * dv + P0r[v * H + h];
    ai = (si[0][h] + si[1][h] + si[2][h] + si[3][h]) * dv + P0i[v * H + h];
    if (ar < 0.f) { ar = 0.f; ai = 0.f; }
    xr[v * H + h] = ar;
    xi[v * H + h] = ai;
  }
}

// -------------------------------------------------------------- layer-2 GEMM
__global__ __launch_bounds__(256) void gemm2_kernel(
    const float* __restrict__ xr, const float* __restrict__ xi,
    const float* __restrict__ W2,
    float* __restrict__ P0r, float* __restrict__ P0i,
    float* __restrict__ P1r, float* __restrict__ P1i)
{
  __shared__ float As[64][65];
  __shared__ float Ws[64][64];
  int bi = blockIdx.x;
  int which = bi & 3, tile = bi >> 2;
  const float* A = (which & 1) ? xi : xr;
  const float* W = W2 + (size_t)(which >> 1) * H * H;
  float* C = (which == 0) ? P0r : (which == 1) ? P0i
           : (which == 2) ? P1r : P1i;
  gemm_tile256(A, W, As, Ws, tile * 64, H, C);
}

// -------------------- layer-2 aggregation + ReLU + per-node partial logits
__global__ __launch_bounds__(256) void aggregate2_kernel(
    const int* __restrict__ cnt, const int* __restrict__ nbr,
    const float* __restrict__ cra, const float* __restrict__ cia,
    const float* __restrict__ deg,
    const float* __restrict__ P0r, const float* __restrict__ P0i,
    const float* __restrict__ P1r, const float* __restrict__ P1i,
    const float* __restrict__ lw, const float* __restrict__ lb,
    float4* __restrict__ nuw)
{
  __shared__ float sr[4][64], si[4][64];
  int v = blockIdx.x;
  int h = threadIdx.x & 63;
  int wv = threadIdx.x >> 6;
  float ar, ai;
  agg_partial(cnt, nbr, cra, cia, deg, P1r, P1i, v, h, wv, ar, ai);
  sr[wv][h] = ar; si[wv][h] = ai;
  __syncthreads();
  if (wv == 0) {
    float dgv = deg[v];
    float dv = (dgv > 0.f) ? rsqrtf(dgv) : 0.f;
    ar = (sr[0][h] + sr[1][h] + sr[2][h] + sr[3][h]) * dv + P0r[v * H + h];
    ai = (si[0][h] + si[1][h] + si[2][h] + si[3][h]) * dv + P0i[v * H + h];
    if (ar < 0.f) { ar = 0.f; ai = 0.f; }
    const float2* lw2 = reinterpret_cast<const float2*>(lw);
    float2 l0 = lw2[h], l1 = lw2[64 + h], l2 = lw2[128 + h], l3 = lw2[192 + h];
    float u0 = ar * l0.x + ai * l2.x;
    float u1 = ar * l0.y + ai * l2.y;
    float w0 = ar * l1.x + ai * l3.x;
    float w1 = ar * l1.y + ai * l3.y;
    #pragma unroll
    for (int off = 1; off < 64; off <<= 1) {
      u0 += __shfl_xor(u0, off, 64);
      u1 += __shfl_xor(u1, off, 64);
      w0 += __shfl_xor(w0, off, 64);
      w1 += __shfl_xor(w1, off, 64);
    }
    if (h == 0)
      nuw[v] = make_float4(u0 + lb[0], u1 + lb[1], w0, w1);
  }
}

// -------------------------------------------------------------- query head
// 16 lanes/query, float4/lane of the 256B sim row; 2-query ILP per iteration.
__global__ __launch_bounds__(256) void query_kernel(
    const int* __restrict__ qe, const float* __restrict__ emb,
    const float* __restrict__ lw, const float4* __restrict__ nuw,
    float2* __restrict__ out, int Qn, int n)
{
  const float2* lw2 = reinterpret_cast<const float2*>(lw);
  int l = threadIdx.x & 15;
  float2 wa = lw2[256 + 4 * l];
  float2 wb = lw2[257 + 4 * l];
  float2 wc = lw2[258 + 4 * l];
  float2 wd = lw2[259 + 4 * l];
  int g0 = (blockIdx.x * 256 + threadIdx.x) >> 4;
  int ng = (gridDim.x * 256) >> 4;
  const float4* emb4 = reinterpret_cast<const float4*>(emb);
  for (int q = g0; q < Qn; q += 2 * ng) {
    int q2 = q + ng;
    bool has2 = q2 < Qn;
    int ni0 = qe[2 * q], nj0 = qe[2 * q + 1];
    int ni1 = has2 ? qe[2 * q2] : ni0;
    int nj1 = has2 ? qe[2 * q2 + 1] : nj0;
    float4 sa = emb4[((size_t)ni0 * n + nj0) * 16 + l];
    float4 sb = emb4[((size_t)ni1 * n + nj1) * 16 + l];
    float a0 = sa.x * wa.x + sa.y * wb.x + sa.z * wc.x + sa.w * wd.x;
    float a1 = sa.x * wa.y + sa.y * wb.y + sa.z * wc.y + sa.w * wd.y;
    float b0 = sb.x * wa.x + sb.y * wb.x + sb.z * wc.x + sb.w * wd.x;
    float b1 = sb.x * wa.y + sb.y * wb.y + sb.z * wc.y + sb.w * wd.y;
    #pragma unroll
    for (int off = 1; off < 16; off <<= 1) {
      a0 += __shfl_xor(a0, off, 64);
      a1 += __shfl_xor(a1, off, 64);
      b0 += __shfl_xor(b0, off, 64);
      b1 += __shfl_xor(b1, off, 64);
    }
    if (l == 0) {
      float4 uni = nuw[ni0];
      float4 unj = nuw[nj0];
      float lg0 = a0 + uni.x + unj.z;
      float lg1 = a1 + uni.y + unj.w;
      float m = fmaxf(lg0, lg1);
      float lse = m + logf(expf(lg0 - m) + expf(lg1 - m));
      out[q] = make_float2(lg0 - lse, lg1 - lse);
      if (has2) {
        float4 uni2 = nuw[ni1];
        float4 unj2 = nuw[nj1];
        float mg0 = b0 + uni2.x + unj2.z;
        float mg1 = b1 + uni2.y + unj2.w;
        float m2 = fmaxf(mg0, mg1);
        float lse2 = m2 + logf(expf(mg0 - m2) + expf(mg1 - m2));
        out[q2] = make_float2(mg0 - lse2, mg1 - lse2);
      }
    }
  }
}

// ------------------------------------------------------------------- launcher
extern "C" void kernel_launch(void* const* d_in, const int* in_sizes, int n_in,
                              void* d_out, int out_size, void* d_ws, size_t ws_size,
                              hipStream_t stream)
{
  const float* real = (const float*)d_in[0];
  const float* imag = (const float*)d_in[1];
  const int*   ei   = (const int*)d_in[2];
  const int*   qe   = (const int*)d_in[3];
  const float* emb  = (const float*)d_in[4];
  const float* ew   = (const float*)d_in[5];
  const float* W1   = (const float*)d_in[6];
  const float* W2   = (const float*)d_in[7];
  const float* lw   = (const float*)d_in[8];
  const float* lb   = (const float*)d_in[9];
  float2* out = (float2*)d_out;

  int E = in_sizes[2] / 2;
  int Q = in_sizes[3] / 2;
  int n = N_NODES;
  int nslots = N_NODES << SLOT_SH;   // 512000

  char* ws = (char*)d_ws;
  size_t off = 0;
  auto alloc = [&](size_t bytes) -> char* {
    char* p = ws + off;
    off = (off + bytes + 255) & ~(size_t)255;
    return p;
  };
  float*  deg = (float*)alloc(2048 * 4);   // deg+cnt adjacent: one 16KB memset
  int*    cnt = (int*)  alloc(2048 * 4);
  int*    nbr = (int*)  alloc((size_t)nslots * 4);
  float*  cra = (float*)alloc((size_t)nslots * 4);
  float*  cia = (float*)alloc((size_t)nslots * 4);
  float*  P0r = (float*)alloc((size_t)n * H * 4);
  float*  P0i = (float*)alloc((size_t)n * H * 4);
  float*  P1r = (float*)alloc((size_t)n * H * 4);
  float*  P1i = (float*)alloc((size_t)n * H * 4);
  float*  xr1 = (float*)alloc((size_t)n * H * 4);
  float*  xi1 = (float*)alloc((size_t)n * H * 4);
  float4* nuw = (float4*)alloc((size_t)n * 16);

  hipMemsetAsync(deg, 0, 2 * 2048 * 4, stream);           // 16 KB only

  int eblocks = (E + 255) / 256;                          // 250
  fused1_kernel<<<128 + eblocks, 256, 0, stream>>>(
      real, imag, W1, ei, ew, deg, cnt, nbr, cra, cia,
      P0r, P0i, P1r, P1i, E);
  aggregate1_kernel<<<n, 256, 0, stream>>>(cnt, nbr, cra, cia, deg,
                                           P0r, P0i, P1r, P1i, xr1, xi1);
  gemm2_kernel<<<128, 256, 0, stream>>>(xr1, xi1, W2, P0r, P0i, P1r, P1i);
  aggregate2_kernel<<<n, 256, 0, stream>>>(cnt, nbr, cra, cia, deg,
                                           P0r, P0i, P1r, P1i, lw, lb, nuw);
  query_kernel<<<2048, 256, 0, stream>>>(qe, emb, lw, nuw, out, Q, n);
}